// Round 6
// baseline (312.138 us; speedup 1.0000x reference)
//
#include <hip/hip_runtime.h>

#define TPB 256
#define PTS 8                   // queries per thread
#define CHUNK 128               // db points per block chunk (G = 64)
#define QTILE (TPB * PTS)       // 2048 queries per tile

typedef float f2 __attribute__((ext_vector_type(2)));

// Forced packed FMA: d = a*b + c per 32-bit half. Same IEEE fma, same chain
// order as all prior verified kernels -> distance bits unchanged.
#define PKFMA(d, a, b, c) \
    asm("v_pk_fma_f32 %0, %1, %2, %3" : "=v"(d) : "v"(a), "v"(b), "v"(c))

// ws layout: part[s][g][mx] floats (4*64*8192 = 8 MB), then
//            uint ctr[ngrp+1], float gsum[ngrp]   (ngrp = 16)

__global__ __launch_bounds__(TPB, 4) void chamfer_nn(
        const float* __restrict__ pos, const float* __restrict__ xhat,
        float* __restrict__ part, unsigned* __restrict__ ctr,
        float* __restrict__ gsum,
        int N, int M, int mx,
        float inv1, float inv2, float* __restrict__ out) {
    const int s   = blockIdx.z;              // stream = b*2 + dir
    const int dir = s & 1, b = s >> 1;
    // dir 0: queries = pos, db = xhat (dist1); dir 1: queries = xhat, db = pos
    const float* __restrict__ A  = dir ? xhat : pos;
    const float* __restrict__ Bp = dir ? pos  : xhat;
    const int NA = dir ? M : N;
    const int NB = dir ? N : M;
    const float invW = dir ? inv2 : inv1;
    const int Gy = gridDim.y;
    float* outp = part + (size_t)(s * Gy + blockIdx.y) * mx;

    // ---- stage db chunk pair-interleaved:
    //      sB4[2p]   = {-2x0, -2x1, -2y0, -2y1}
    //      sB4[2p+1] = {-2z0, -2z1,  n0,   n1 }
    __shared__ float4 sB4[CHUNK];            // 2 KB
    const int mbase = blockIdx.y * CHUNK;
    const int mlen  = min(CHUNK, NB - mbase);
    const int pairs = mlen > 0 ? (mlen + 1) >> 1 : 0;
    const float* dbase = Bp + (size_t)(b * NB + mbase) * 3;
    for (int p = threadIdx.x; p < pairs; p += TPB) {
        int j0 = 2 * p, j1 = min(2 * p + 1, mlen - 1);
        const float* p0 = dbase + j0 * 3;
        const float* p1 = dbase + j1 * 3;
        float x0 = p0[0], y0 = p0[1], z0 = p0[2];
        float x1 = p1[0], y1 = p1[1], z1 = p1[2];
        sB4[2 * p]     = make_float4(-2.0f * x0, -2.0f * x1,
                                     -2.0f * y0, -2.0f * y1);
        sB4[2 * p + 1] = make_float4(-2.0f * z0, -2.0f * z1,
                                     x0 * x0 + y0 * y0 + z0 * z0,
                                     x1 * x1 + y1 * y1 + z1 * z1);
    }

    // ---- queries: loop-invariant splat pairs (built once, no inner movs) ----
    const int i0 = blockIdx.x * QTILE + threadIdx.x;
    f2 qx[PTS], qy[PTS], qz[PTS];
    float cav[PTS], mnv[PTS];
#pragma unroll
    for (int k = 0; k < PTS; k++) {
        int i  = i0 + k * TPB;
        int ic = i < NA ? i : NA - 1;        // clamp; masked at store
        const float* p = A + (size_t)(b * NA + ic) * 3;
        float x = p[0], y = p[1], z = p[2];
        qx[k] = (f2){x, x}; qy[k] = (f2){y, y}; qz[k] = (f2){z, z};
        cav[k] = x * x + y * y + z * z;
        mnv[k] = 3.4e38f;
    }
    __syncthreads();

    // ---- core: 2 db points/iter, 8 queries, all-packed FMA ----
    const f2* sp = (const f2*)sB4;
#pragma unroll 2
    for (int p = 0; p < pairs; ++p) {
        f2 xx = sp[4 * p + 0];
        f2 yy = sp[4 * p + 1];
        f2 zz = sp[4 * p + 2];
        f2 ww = sp[4 * p + 3];
#pragma unroll
        for (int k = 0; k < PTS; k++) {
            f2 sv;
            PKFMA(sv, zz, qz[k], ww);        // az*(-2bz) + |b|^2 (both pts)
            PKFMA(sv, yy, qy[k], sv);
            PKFMA(sv, xx, qx[k], sv);
            mnv[k] = fminf(fminf(mnv[k], sv[0]), sv[1]);   // v_min3
        }
    }

    // ---- store per-query chunk-min distance (coalesced) ----
#pragma unroll
    for (int k = 0; k < PTS; k++) {
        int i = i0 + k * TPB;
        if (i < NA)
            outp[i] = fmaxf(cav[k] + mnv[k], 0.0f);
    }

    // ---- last-block-in-group reduces across g (device-scope handshake) ----
    __threadfence();                          // release partial stores
    __shared__ unsigned lastFlag;
    const int tiles = gridDim.x;
    const int gi = s * tiles + blockIdx.x;    // 16 groups
    if (threadIdx.x == 0) {
        unsigned prev = __hip_atomic_fetch_add(&ctr[gi], 1u,
                            __ATOMIC_ACQ_REL, __HIP_MEMORY_SCOPE_AGENT);
        lastFlag = (prev == (unsigned)Gy - 1);
    }
    __syncthreads();
    if (!lastFlag) return;
    __threadfence();                          // acquire before reading others'

    float ssum = 0.0f;
    const float* pbase = part + (size_t)s * Gy * mx;
#pragma unroll
    for (int k = 0; k < PTS; k++) {
        int i = i0 + k * TPB;                 // this tile's queries
        if (i < NA) {
            float mn = 3.4e38f;
            for (int g = 0; g < Gy; ++g)      // coalesced across threads
                mn = fminf(mn, pbase[(size_t)g * mx + i]);
            ssum += mn;
        }
    }
    ssum *= invW;

    __shared__ float sh[TPB];
    sh[threadIdx.x] = ssum;
    __syncthreads();
    for (int off = TPB / 2; off > 0; off >>= 1) {
        if (threadIdx.x < off) sh[threadIdx.x] += sh[threadIdx.x + off];
        __syncthreads();
    }
    if (threadIdx.x == 0) {
        const int ngrp = gridDim.z * tiles;   // 16
        gsum[gi] = sh[0];
        __threadfence();                      // release gsum
        unsigned fprev = __hip_atomic_fetch_add(&ctr[ngrp], 1u,
                             __ATOMIC_ACQ_REL, __HIP_MEMORY_SCOPE_AGENT);
        if (fprev == (unsigned)ngrp - 1) {
            __threadfence();                  // acquire gsum[*]
            float tot = 0.0f;
            for (int g2 = 0; g2 < ngrp; ++g2) tot += gsum[g2];
            out[0] = tot;                     // loss
            out[1] = tot;                     // rec_loss (identical)
        }
    }
}

extern "C" void kernel_launch(void* const* d_in, const int* in_sizes, int n_in,
                              void* d_out, int out_size, void* d_ws, size_t ws_size,
                              hipStream_t stream) {
    const float* pos  = (const float*)d_in[0];
    const float* xhat = (const float*)d_in[1];
    const int B = 2;
    const int N = in_sizes[0] / (B * 3);   // 8192
    const int M = in_sizes[1] / (B * 3);   // 8192
    float* out = (float*)d_out;

    const int mx    = N > M ? N : M;
    const int tiles = (mx + QTILE - 1) / QTILE;    // 4
    const int G     = (mx + CHUNK - 1) / CHUNK;    // 64
    const int ngrp  = B * 2 * tiles;               // 16

    float*    part = (float*)d_ws;
    const size_t part_floats = (size_t)(B * 2) * G * mx;   // 8 MB / 4
    unsigned* ctr  = (unsigned*)(part + part_floats);
    float*    gsum = (float*)(ctr + ngrp + 1);

    // zero the done-counters (68 B) — ws is harness-poisoned each iteration
    (void)hipMemsetAsync(ctr, 0, (size_t)(ngrp + 1) * sizeof(unsigned), stream);

    dim3 grid(tiles, G, B * 2);                    // 1024 blocks, 4 waves/SIMD
    chamfer_nn<<<grid, TPB, 0, stream>>>(pos, xhat, part, ctr, gsum,
                                         N, M, mx,
                                         1.0f / (B * N), 1.0f / (B * M), out);
}

// Round 7
// 85.141 us; speedup vs baseline: 3.6661x; 3.6661x over previous
//
#include <hip/hip_runtime.h>

#define TPB 256
#define PTS 8                   // queries per thread
#define CHUNK 128               // db points per block chunk (G = 64)
#define QTILE (TPB * PTS)       // 2048 queries per tile

typedef float f2 __attribute__((ext_vector_type(2)));

// Forced packed FMA: d = a*b + c per 32-bit half. Same IEEE fma, same chain
// order as all prior verified kernels -> distance bits unchanged (absmax 0.0
// verified in round 6).
#define PKFMA(d, a, b, c) \
    asm("v_pk_fma_f32 %0, %1, %2, %3" : "=v"(d) : "v"(a), "v"(b), "v"(c))

// ws layout: part[s][g][mx] floats (4 * 64 * 8192 * 4B = 8 MB)

__global__ __launch_bounds__(TPB, 4) void chamfer_nn(
        const float* __restrict__ pos, const float* __restrict__ xhat,
        float* __restrict__ part, int N, int M, int mx,
        float* __restrict__ out) {
    // zero the output accumulators (stream-ordered before reduce_loss;
    // kernel boundary is the fence — round-0-proven pattern)
    if (blockIdx.x == 0 && blockIdx.y == 0 && blockIdx.z == 0 && threadIdx.x == 0) {
        out[0] = 0.0f; out[1] = 0.0f;
    }
    const int s   = blockIdx.z;              // stream = b*2 + dir
    const int dir = s & 1, b = s >> 1;
    // dir 0: queries = pos, db = xhat (dist1); dir 1: queries = xhat, db = pos
    const float* __restrict__ A  = dir ? xhat : pos;
    const float* __restrict__ Bp = dir ? pos  : xhat;
    const int NA = dir ? M : N;
    const int NB = dir ? N : M;
    const int Gy = gridDim.y;
    float* outp = part + (size_t)(s * Gy + blockIdx.y) * mx;

    // ---- stage db chunk pair-interleaved:
    //      sB4[2p]   = {-2x0, -2x1, -2y0, -2y1}
    //      sB4[2p+1] = {-2z0, -2z1,  n0,   n1 }
    __shared__ float4 sB4[CHUNK];            // 2 KB
    const int mbase = blockIdx.y * CHUNK;
    const int mlen  = min(CHUNK, NB - mbase);
    const int pairs = (mlen + 1) >> 1;       // 64 here
    const float* dbase = Bp + (size_t)(b * NB + mbase) * 3;
    for (int p = threadIdx.x; p < pairs; p += TPB) {
        int j0 = 2 * p, j1 = min(2 * p + 1, mlen - 1);
        const float* p0 = dbase + j0 * 3;
        const float* p1 = dbase + j1 * 3;
        float x0 = p0[0], y0 = p0[1], z0 = p0[2];
        float x1 = p1[0], y1 = p1[1], z1 = p1[2];
        sB4[2 * p]     = make_float4(-2.0f * x0, -2.0f * x1,
                                     -2.0f * y0, -2.0f * y1);
        sB4[2 * p + 1] = make_float4(-2.0f * z0, -2.0f * z1,
                                     x0 * x0 + y0 * y0 + z0 * z0,
                                     x1 * x1 + y1 * y1 + z1 * z1);
    }

    // ---- queries: loop-invariant splat pairs (built once, no inner movs) ----
    const int i0 = blockIdx.x * QTILE + threadIdx.x;
    f2 qx[PTS], qy[PTS], qz[PTS];
    float cav[PTS], mnv[PTS];
#pragma unroll
    for (int k = 0; k < PTS; k++) {
        int i  = i0 + k * TPB;
        int ic = i < NA ? i : NA - 1;        // clamp; masked at store
        const float* p = A + (size_t)(b * NA + ic) * 3;
        float x = p[0], y = p[1], z = p[2];
        qx[k] = (f2){x, x}; qy[k] = (f2){y, y}; qz[k] = (f2){z, z};
        cav[k] = x * x + y * y + z * z;
        mnv[k] = 3.4e38f;
    }
    __syncthreads();

    // ---- core: 2 db points/iter, 8 queries, all-packed FMA ----
    const f2* sp = (const f2*)sB4;
#pragma unroll 2
    for (int p = 0; p < pairs; ++p) {
        f2 xx = sp[4 * p + 0];
        f2 yy = sp[4 * p + 1];
        f2 zz = sp[4 * p + 2];
        f2 ww = sp[4 * p + 3];
#pragma unroll
        for (int k = 0; k < PTS; k++) {
            f2 sv;
            PKFMA(sv, zz, qz[k], ww);        // az*(-2bz) + |b|^2 (both pts)
            PKFMA(sv, yy, qy[k], sv);
            PKFMA(sv, xx, qx[k], sv);
            mnv[k] = fminf(fminf(mnv[k], sv[0]), sv[1]);   // v_min3
        }
    }

    // ---- store per-query chunk-min distance (coalesced) ----
#pragma unroll
    for (int k = 0; k < PTS; k++) {
        int i = i0 + k * TPB;
        if (i < NA)
            outp[i] = fmaxf(cav[k] + mnv[k], 0.0f);
    }
}

__global__ void reduce_loss(const float* __restrict__ part,
                            int N, int M, int mx, int G, int nbz,
                            float inv1, float inv2, float* __restrict__ out) {
    const int total  = nbz * mx;
    const int stride = gridDim.x * blockDim.x;
    float s = 0.0f;
    for (int t = blockIdx.x * blockDim.x + threadIdx.x; t < total; t += stride) {
        int bz = t / mx;
        int i  = t - bz * mx;
        int dir = bz & 1;
        int NA  = dir ? M : N;
        if (i < NA) {
            const float* p = part + (size_t)(bz * G) * mx + i;
            // 4 independent min chains for MLP; min is order-invariant
            float m0 = 3.4e38f, m1 = 3.4e38f, m2 = 3.4e38f, m3 = 3.4e38f;
            int g = 0;
            for (; g + 4 <= G; g += 4) {
                m0 = fminf(m0, p[(size_t)(g + 0) * mx]);
                m1 = fminf(m1, p[(size_t)(g + 1) * mx]);
                m2 = fminf(m2, p[(size_t)(g + 2) * mx]);
                m3 = fminf(m3, p[(size_t)(g + 3) * mx]);
            }
            for (; g < G; ++g)
                m0 = fminf(m0, p[(size_t)g * mx]);
            float mn = fminf(fminf(m0, m1), fminf(m2, m3));
            s += mn * (dir ? inv2 : inv1);
        }
    }
    __shared__ float sh[TPB];
    sh[threadIdx.x] = s;
    __syncthreads();
    for (int off = TPB / 2; off > 0; off >>= 1) {
        if (threadIdx.x < off) sh[threadIdx.x] += sh[threadIdx.x + off];
        __syncthreads();
    }
    if (threadIdx.x == 0) {
        atomicAdd(&out[0], sh[0]);   // loss
        atomicAdd(&out[1], sh[0]);   // rec_loss (identical)
    }
}

extern "C" void kernel_launch(void* const* d_in, const int* in_sizes, int n_in,
                              void* d_out, int out_size, void* d_ws, size_t ws_size,
                              hipStream_t stream) {
    const float* pos  = (const float*)d_in[0];
    const float* xhat = (const float*)d_in[1];
    const int B = 2;
    const int N = in_sizes[0] / (B * 3);   // 8192
    const int M = in_sizes[1] / (B * 3);   // 8192
    float* out  = (float*)d_out;
    float* part = (float*)d_ws;

    const int mx    = N > M ? N : M;
    const int tiles = (mx + QTILE - 1) / QTILE;    // 4
    const int G     = (mx + CHUNK - 1) / CHUNK;    // 64

    dim3 grid(tiles, G, B * 2);                    // 1024 blocks, 4 waves/SIMD
    chamfer_nn<<<grid, TPB, 0, stream>>>(pos, xhat, part, N, M, mx, out);

    reduce_loss<<<128, TPB, 0, stream>>>(part, N, M, mx, G, B * 2,
                                         1.0f / (B * N), 1.0f / (B * M), out);
}